// Round 10
// baseline (401.726 us; speedup 1.0000x reference)
//
#include <hip/hip_runtime.h>
#include <cstdint>
#include <cstddef>

typedef __bf16 bf16;
typedef __bf16 bf16x8 __attribute__((ext_vector_type(8)));
typedef __bf16 bf16x4 __attribute__((ext_vector_type(4)));
typedef float f32x4 __attribute__((ext_vector_type(4)));

#define TOKENS 4096   // B*T
#define TSEQ   2048
#define NHEADS 16
#define HDIM   64
#define CDIM   1024

// ---- async global->LDS, 16B per lane ----
typedef __attribute__((address_space(3))) unsigned int lds_uint;
typedef __attribute__((address_space(1))) const unsigned int g_uint;
__device__ __forceinline__ void glds16(const bf16* g, bf16* l) {
  __builtin_amdgcn_global_load_lds((g_uint*)g, (lds_uint*)l, 16, 0, 0);
}

// fast GELU: x*sigmoid(1.5957691x + 0.0713548x^3); max dev from erf-GELU ~3e-4
__device__ __forceinline__ float gelu_f(float v) {
  float g2 = v * (1.5957691216f + 0.0713548163f * v * v);
  return v / (1.0f + __expf(-g2));
}

// ------------------------------------------------------------------
// Input dtype detection (insurance; fp32 -> flag 0). See round-2 note.
// ------------------------------------------------------------------
#define NBUF 17
struct DetectArgs { const void* p[NBUF]; int n[NBUF]; };

__global__ __launch_bounds__(256) void detect_kernel(DetectArgs a, int* __restrict__ flags) {
  __shared__ int s_nz, s_bl;
  if (threadIdx.x == 0) { s_nz = 0; s_bl = 0; }
  __syncthreads();
  int i = blockIdx.x;
  const unsigned int* w = (const unsigned int*)a.p[i];
  int nwords = a.n[i] / 2; if (nwords > 2048) nwords = 2048;
  int nz = 0, bl = 0;
  for (int j = threadIdx.x; j < nwords; j += 256) {
    unsigned int v = w[j];
    if (v != 0u) {
      nz++;
      unsigned int e = (v >> 7) & 0xFFu;
      if (e >= 100u && e <= 140u) bl++;
    }
  }
  atomicAdd(&s_nz, nz);
  atomicAdd(&s_bl, bl);
  __syncthreads();
  if (threadIdx.x == 0) flags[i] = (2 * s_bl >= s_nz) ? 1 : 0;
}

__device__ __forceinline__ float ld_any(const void* p, size_t idx, bool isb) {
  return isb ? (float)((const bf16*)p)[idx] : ((const float*)p)[idx];
}

// ------------------------------------------------------------------
// LayerNorm stats (rows of 1024, 256 threads): returns mu, rstd
// ------------------------------------------------------------------
__device__ __forceinline__ void ln_stats(float s, float s2, int tid, float& mu, float& rstd) {
#pragma unroll
  for (int off = 32; off; off >>= 1) {
    s  += __shfl_down(s, off);
    s2 += __shfl_down(s2, off);
  }
  __shared__ float red[8];
  int w = tid >> 6;
  if ((tid & 63) == 0) { red[w] = s; red[4 + w] = s2; }
  __syncthreads();
  if (tid == 0) {
    red[0] = red[0] + red[1] + red[2] + red[3];
    red[4] = red[4] + red[5] + red[6] + red[7];
  }
  __syncthreads();
  mu = red[0] * (1.0f / CDIM);
  float var = fmaxf(red[4] * (1.0f / CDIM) - mu * mu, 0.f);
  rstd = rsqrtf(var + 1e-5f);
}

__global__ __launch_bounds__(256) void ln_f32(const float* __restrict__ x,
                                              const bf16* __restrict__ g,
                                              const bf16* __restrict__ b,
                                              bf16* __restrict__ y) {
  int row = blockIdx.x, tid = threadIdx.x;
  float v[4]; float s = 0.f, s2 = 0.f;
#pragma unroll
  for (int i = 0; i < 4; i++) {
    float f = x[(size_t)row * CDIM + tid * 4 + i];
    v[i] = f; s += f; s2 += f * f;
  }
  float mu, rstd;
  ln_stats(s, s2, tid, mu, rstd);
  bf16* yr = y + (size_t)row * CDIM;
#pragma unroll
  for (int i = 0; i < 4; i++) {
    int c = tid * 4 + i;
    yr[c] = (bf16)((v[i] - mu) * rstd * (float)g[c] + (float)b[c]);
  }
}

// ------------------------------------------------------------------
// Mega preprocessing kernel (ONE launch). LN1 reads gamma/beta from RAW
// inputs (race-fix, round 8). Blocks: [0,3072) transposes, 3072 vec
// converts, (3072, 3072+4096] LN1.
// ------------------------------------------------------------------
struct MegaArgs {
  const void* w_in[6]; bf16* w_out[6]; int wK[6], wN[6], wflag[6];
  const void* vp[10]; bf16* vd[10]; int vn[10], vfi[10];
  const void* x; const void* graw; const void* braw; bf16* y;
};

__global__ __launch_bounds__(256) void mega_pre(MegaArgs a, const int* __restrict__ flags) {
  int bid = blockIdx.x;
  int tx = threadIdx.x, ty = threadIdx.y;          // blockDim (64,4)
  int tid = tx + ty * 64;
  if (bid < 3072) {
    __shared__ bf16 tile[64][65];
    int mi, start;
    if (bid < 1024)      { mi = bid >> 8; start = mi << 8; }
    else if (bid < 2048) { mi = 4; start = 1024; }
    else                 { mi = 5; start = 2048; }
    int tb = bid - start;
    int nT = a.wN[mi] >> 6;
    int kb = (tb / nT) * 64, nb = (tb % nT) * 64;
    int K = a.wK[mi], N = a.wN[mi];
    bool isb = flags[a.wflag[mi]] != 0;
    const void* in = a.w_in[mi]; bf16* out = a.w_out[mi];
    for (int i = ty; i < 64; i += 4)
      tile[i][tx] = (bf16)ld_any(in, (size_t)(kb + i) * N + nb + tx, isb);
    __syncthreads();
    for (int i = ty; i < 64; i += 4)
      out[(size_t)(nb + i) * K + kb + tx] = tile[tx][i];
  } else if (bid == 3072) {
    for (int i = 0; i < 10; i++) {
      bool isb = flags[a.vfi[i]] != 0;
      const void* in = a.vp[i]; bf16* out = a.vd[i]; int n = a.vn[i];
      for (int j = tid; j < n; j += 256)
        out[j] = (bf16)ld_any(in, j, isb);
    }
  } else {
    int row = bid - 3073;
    bool isb  = flags[0] != 0;
    bool gisb = flags[1] != 0;
    bool bisb = flags[2] != 0;
    float v[4]; float s = 0.f, s2 = 0.f;
#pragma unroll
    for (int i = 0; i < 4; i++) {
      float f = ld_any(a.x, (size_t)row * CDIM + tid * 4 + i, isb);
      v[i] = f; s += f; s2 += f * f;
    }
    float mu, rstd;
    ln_stats(s, s2, tid, mu, rstd);
    bf16* yr = a.y + (size_t)row * CDIM;
#pragma unroll
    for (int i = 0; i < 4; i++) {
      int c = tid * 4 + i;
      float gv = ld_any(a.graw, c, gisb);
      float bv = ld_any(a.braw, c, bisb);
      yr[c] = (bf16)((v[i] - mu) * rstd * gv + bv);
    }
  }
}

// ------------------------------------------------------------------
// GEMM core, BK=64 (two BK=32 panels per barrier-pair), glds staging,
// XOR-chunk swizzle (proven round 6/7)
// ------------------------------------------------------------------
template <int BM, int BN>
__device__ __forceinline__ void gemm_core(const bf16* __restrict__ A,
                                          const bf16* __restrict__ Bt,
                                          int K, int m0, int n0,
                                          bf16* As, bf16* Bs,
                                          f32x4 (&acc)[BM / 32][BN / 32]) {
  constexpr int SI = BM / 32, SJ = BN / 32;
  int t = threadIdx.x;
  int wave = t >> 6, lane = t & 63, quad = lane >> 4, l16 = lane & 15;
  int wm = (wave & 1) * (BM / 2), wn = (wave >> 1) * (BN / 2);
  int srow = t >> 2, sc = t & 3;
  int swz = (srow >> 1) & 3;
  const bf16* ga[BM / 64];
  const bf16* gb[BN / 64];
#pragma unroll
  for (int h = 0; h < BM / 64; h++)
    ga[h] = A + (size_t)(m0 + h * 64 + srow) * K + (sc ^ swz) * 8;
#pragma unroll
  for (int h = 0; h < BN / 64; h++)
    gb[h] = Bt + (size_t)(n0 + h * 64 + srow) * K + (sc ^ swz) * 8;

  for (int k0 = 0; k0 < K; k0 += 64) {
#pragma unroll
    for (int q = 0; q < 2; q++) {
#pragma unroll
      for (int h = 0; h < BM / 64; h++)
        glds16(ga[h] + k0 + q * 32, As + q * (BM * 32) + h * 2048 + srow * 32 + sc * 8);
#pragma unroll
      for (int h = 0; h < BN / 64; h++)
        glds16(gb[h] + k0 + q * 32, Bs + q * (BN * 32) + h * 2048 + srow * 32 + sc * 8);
    }
    __syncthreads();
#pragma unroll
    for (int q = 0; q < 2; q++) {
      bf16x8 af[SI], bfr[SJ];
#pragma unroll
      for (int i = 0; i < SI; i++) {
        int m = wm + i * 16 + l16;
        af[i] = *(const bf16x8*)&As[q * (BM * 32) + m * 32 + ((quad ^ ((m >> 1) & 3)) * 8)];
      }
#pragma unroll
      for (int j = 0; j < SJ; j++) {
        int n = wn + j * 16 + l16;
        bfr[j] = *(const bf16x8*)&Bs[q * (BN * 32) + n * 32 + ((quad ^ ((n >> 1) & 3)) * 8)];
      }
#pragma unroll
      for (int i = 0; i < SI; i++)
#pragma unroll
        for (int j = 0; j < SJ; j++)
          acc[i][j] = __builtin_amdgcn_mfma_f32_16x16x32_bf16(af[i], bfr[j], acc[i][j], 0, 0, 0);
    }
    __syncthreads();
  }
}

#define EPI_NONE 0
#define EPI_RES  1
#define EPI_GELU 2

template <int BM, int BN, int EPI, typename OutT, typename ResT>
__global__ __launch_bounds__(256) void gemm128(const bf16* __restrict__ A,
                                               const bf16* __restrict__ Bt,
                                               const bf16* __restrict__ bias,
                                               const ResT* __restrict__ res,
                                               OutT* __restrict__ C,
                                               int N, int K) {
  __shared__ alignas(16) bf16 As[2 * BM * 32];
  __shared__ alignas(16) bf16 Bs[2 * BN * 32];
  int m0 = blockIdx.y * BM, n0 = blockIdx.x * BN;
  f32x4 acc[BM / 32][BN / 32] = {};
  gemm_core<BM, BN>(A, Bt, K, m0, n0, As, Bs, acc);

  int t = threadIdx.x, wave = t >> 6, lane = t & 63, quad = lane >> 4, l16 = lane & 15;
  int wm = (wave & 1) * (BM / 2), wn = (wave >> 1) * (BN / 2);
#pragma unroll
  for (int i = 0; i < BM / 32; i++)
#pragma unroll
    for (int j = 0; j < BN / 32; j++) {
      int n = n0 + wn + j * 16 + l16;
      float bv = (float)bias[n];
#pragma unroll
      for (int r = 0; r < 4; r++) {
        int m = m0 + wm + i * 16 + quad * 4 + r;
        float v = acc[i][j][r] + bv;
        if (EPI == EPI_GELU)      v = gelu_f(v);
        else if (EPI == EPI_RES)  v += (float)res[(size_t)m * N + n];
        C[(size_t)m * N + n] = (OutT)v;
      }
    }
}

// QKV GEMM. Q cols (n<1024) pre-scaled by 1/8 (exact, pow2) so attention
// needs no score scaling. V cols (n>=2048) written transposed [d][token].
__global__ __launch_bounds__(256) void gemm_qkv(const bf16* __restrict__ A,
                                                const bf16* __restrict__ Bt,
                                                const bf16* __restrict__ bias,
                                                bf16* __restrict__ QK,
                                                bf16* __restrict__ Vt) {
  __shared__ alignas(16) bf16 As[2 * 128 * 32];
  __shared__ alignas(16) bf16 Bs[2 * 128 * 32];
  int m0 = blockIdx.y * 128, n0 = blockIdx.x * 128;
  f32x4 acc[4][4] = {};
  gemm_core<128, 128>(A, Bt, 1024, m0, n0, As, Bs, acc);

  int t = threadIdx.x, wave = t >> 6, lane = t & 63, quad = lane >> 4, l16 = lane & 15;
  int wm = (wave & 1) * 64, wn = (wave >> 1) * 64;
#pragma unroll
  for (int i = 0; i < 4; i++)
#pragma unroll
    for (int j = 0; j < 4; j++) {
      int n = n0 + wn + j * 16 + l16;
      float bv = (float)bias[n];
      int mb = m0 + wm + i * 16 + quad * 4;
      if (n < 1024) {
#pragma unroll
        for (int r = 0; r < 4; r++)
          QK[(size_t)(mb + r) * 2048 + n] = (bf16)((acc[i][j][r] + bv) * 0.125f);
      } else if (n < 2048) {
#pragma unroll
        for (int r = 0; r < 4; r++)
          QK[(size_t)(mb + r) * 2048 + n] = (bf16)(acc[i][j][r] + bv);
      } else {
        bf16x4 pk;
#pragma unroll
        for (int r = 0; r < 4; r++) pk[r] = (bf16)(acc[i][j][r] + bv);
        *(bf16x4*)&Vt[(size_t)(n - 2048) * TOKENS + mb] = pk;
      }
    }
}

// ------------------------------------------------------------------
// Flash attention v5: 8 waves x 32 q-rows = 256 q/block, 64-key tiles.
// S^T = K*Q^T (C-layout gives lane P^T[key=quad*4+r+16c][qrow=l16]).
// PV uses MFMA k-slot permutation pi(quad*8+j) = quad*4+(j&3)+16(j>>2):
// exp'd S^T registers ARE the PV B-frag (no P LDS round-trip at all);
// matching V^T A-frags are 2xb64 LDS reads, independent of exp.
// Row sums accumulate in-lane; 2 shuffles at the end (keys partition
// across quads). No Ps buffer: LDS 32KB, grid 256 = 1 block/CU.
// ------------------------------------------------------------------
__global__ __launch_bounds__(512) void attn_kernel(const bf16* __restrict__ QK,
                                                   const bf16* __restrict__ Vt,
                                                   bf16* __restrict__ O) {
  __shared__ alignas(16) bf16 Ks[2][4096];      // [key][d] 64x64, XOR-swizzled
  __shared__ alignas(16) bf16 Vs[2][4096];      // [d][key] 64x64, XOR-swizzled
  int b = blockIdx.z, h = blockIdx.y, q0 = blockIdx.x * 256;
  int t = threadIdx.x, wave = t >> 6, lane = t & 63, quad = lane >> 4, l16 = lane & 15;

  const bf16* Qg = QK;
  const bf16* Kg = QK + 1024;
  const size_t bT = (size_t)b * TSEQ;
  const int h64 = h * 64;

  // staging: wave w stages rows w*8..w*8+7; 1 glds16/lane/matrix/iter
  int srow = wave * 8 + (lane >> 3);
  int schunk = (lane & 7) ^ (srow & 7);

  // Q fragments: qf[qsub][kchunk] = Q[qrow = q0+wave*32+qsub*16+l16][d = kchunk*32+quad*8 ..+7]
  bf16x8 qf[2][2];
#pragma unroll
  for (int qs = 0; qs < 2; qs++) {
    size_t qrow = bT + q0 + wave * 32 + qs * 16 + l16;
#pragma unroll
    for (int kc = 0; kc < 2; kc++)
      qf[qs][kc] = *(const bf16x8*)&Qg[qrow * 2048 + h64 + kc * 32 + quad * 8];
  }

  f32x4 accOT[4][2] = {};   // [dblk][qsub]; lane holds O^T[d=16dblk+quad*4+r][qrow=l16+16qsub]
  float accL[2] = {0.f, 0.f};

  auto stage = [&](int tile, int buf) {
    glds16(&Kg[(bT + tile * 64 + srow) * 2048 + h64 + schunk * 8],
           &Ks[buf][wave * 512 + lane * 8]);
    glds16(&Vt[(size_t)(h64 + srow) * TOKENS + bT + tile * 64 + schunk * 8],
           &Vs[buf][wave * 512 + lane * 8]);
  };

  int sw = l16 & 7;

  stage(0, 0);
  __syncthreads();

  for (int it = 0; it < TSEQ / 64; it++) {
    int cur = it & 1;
    if (it + 1 < TSEQ / 64) stage(it + 1, cur ^ 1);

    const bf16* KsC = &Ks[cur][0];
    const bf16* VsC = &Vs[cur][0];

    // V^T A-frags (independent of S/exp -> issue early):
    // vf[dblk][pvk][j] = V[key = pi(quad*8+j)+32pvk][d = l16+16dblk]
    bf16x8 vf[4][2];
#pragma unroll
    for (int dblk = 0; dblk < 4; dblk++) {
      int row = (l16 + 16 * dblk) * 64;
#pragma unroll
      for (int pvk = 0; pvk < 2; pvk++) {
        int lcl = (quad >> 1) + 4 * pvk;
        bf16x4 lo = *(const bf16x4*)&VsC[row + ((lcl ^ sw) * 8) + (quad & 1) * 4];
        bf16x4 hi = *(const bf16x4*)&VsC[row + (((lcl + 2) ^ sw) * 8) + (quad & 1) * 4];
        bf16x8 v;
#pragma unroll
        for (int j = 0; j < 4; j++) { v[j] = lo[j]; v[4 + j] = hi[j]; }
        vf[dblk][pvk] = v;
      }
    }

    // S^T = K * Q^T : lane gets S^T[key = 16c+quad*4+r][qrow = l16+16qs]
    f32x4 ST[4][2];
#pragma unroll
    for (int c = 0; c < 4; c++) {
      int row = (c * 16 + l16) * 64;
      bf16x8 kb0 = *(const bf16x8*)&KsC[row + ((quad ^ sw) * 8)];
      bf16x8 kb1 = *(const bf16x8*)&KsC[row + (((quad + 4) ^ sw) * 8)];
#pragma unroll
      for (int qs = 0; qs < 2; qs++) {
        f32x4 s = {};
        s = __builtin_amdgcn_mfma_f32_16x16x32_bf16(kb0, qf[qs][0], s, 0, 0, 0);
        s = __builtin_amdgcn_mfma_f32_16x16x32_bf16(kb1, qf[qs][1], s, 0, 0, 0);
        ST[c][qs] = s;
      }
    }

    // exp in registers; pack PV B-frags; accumulate in-lane row sums
#pragma unroll
    for (int qs = 0; qs < 2; qs++) {
      bf16x8 pf[2];
      float ls = 0.f;
#pragma unroll
      for (int c = 0; c < 4; c++)
#pragma unroll
        for (int r = 0; r < 4; r++) {
          float p = __expf(fminf(ST[c][qs][r], 60.f));
          ls += p;
          pf[c >> 1][(c & 1) * 4 + r] = (bf16)p;
        }
      accL[qs] += ls;
#pragma unroll
      for (int dblk = 0; dblk < 4; dblk++) {
        accOT[dblk][qs] = __builtin_amdgcn_mfma_f32_16x16x32_bf16(vf[dblk][0], pf[0], accOT[dblk][qs], 0, 0, 0);
        accOT[dblk][qs] = __builtin_amdgcn_mfma_f32_16x16x32_bf16(vf[dblk][1], pf[1], accOT[dblk][qs], 0, 0, 0);
      }
    }

    __syncthreads();
  }

  // finalize: cross-quad key-partition reduce for l, then normalized store
#pragma unroll
  for (int qs = 0; qs < 2; qs++) {
    float l = accL[qs];
    l += __shfl_xor(l, 16);
    l += __shfl_xor(l, 32);
    float rinv = 1.0f / fmaxf(l, 1e-30f);
    size_t token = bT + q0 + wave * 32 + qs * 16 + l16;
#pragma unroll
    for (int dblk = 0; dblk < 4; dblk++) {
      bf16x4 pk;
#pragma unroll
      for (int r = 0; r < 4; r++) pk[r] = (bf16)(accOT[dblk][qs][r] * rinv);
      *(bf16x4*)&O[token * CDIM + h64 + dblk * 16 + quad * 4] = pk;
    }
  }
}

// ------------------------------------------------------------------
extern "C" void kernel_launch(void* const* d_in, const int* in_sizes, int n_in,
                              void* d_out, int out_size, void* d_ws, size_t ws_size,
                              hipStream_t stream) {
  char* ws = (char*)d_ws;
  const size_t MB = 1024 * 1024;
  const size_t KB = 1024;

  int* flags = (int*)ws;
  bf16* vec_c = (bf16*)(ws + 4 * KB);
  bf16* ln1g_c = vec_c + 0 * 8192;
  bf16* ln1b_c = vec_c + 1 * 8192;
  bf16* ln2g_c = vec_c + 2 * 8192;
  bf16* ln2b_c = vec_c + 3 * 8192;
  bf16* bqkv_c = vec_c + 4 * 8192;            // [3072]: bq | bk | bv
  bf16* bo_c   = vec_c + 6 * 8192;
  bf16* b1_c   = vec_c + 7 * 8192;
  bf16* b2_c   = vec_c + 8 * 8192;

  bf16*  WqkvT  = (bf16*)(ws + 1 * MB);       // [3072][1024]  1-7
  bf16*  WoT    = (bf16*)(ws + 7 * MB);       // 7-9
  bf16*  W1T    = (bf16*)(ws + 9 * MB);       // 9-17
  bf16*  W2T    = (bf16*)(ws + 17 * MB);      // 17-25
  bf16*  xn     = (bf16*)(ws + 25 * MB);      // 25-33  (live until Wo GEMM)
  bf16*  QKbuf  = (bf16*)(ws + 33 * MB);      // [4096][2048] 33-49 (dead after attn)
  bf16*  Vtbuf  = (bf16*)(ws + 49 * MB);      // [1024][4096] 49-57 (dead after attn)
  bf16*  ab     = (bf16*)(ws + 57 * MB);      // 57-65 (dead after Wo GEMM)
  float* xmid32 = (float*)(ws + 65 * MB);     // 65-81 fp32
  bf16*  h2     = (bf16*)(ws + 81 * MB);      // 81-89
  bf16*  f1     = (bf16*)(ws + 33 * MB);      // [4096][4096] 33-65 (reuses dead bufs)

  // flag idx: 0 x,1 ln1g,2 ln1b,3 ln2g,4 ln2b,5 Wq,6 bq,7 Wk,8 bk,9 Wv,10 bv,
  //           11 Wo,12 bo,13 W1,14 b1,15 W2,16 b2
  const int din_idx[NBUF] = {0, 2, 3, 4, 5, 6, 7, 8, 9, 10, 11, 12, 13, 14, 15, 16, 17};
  DetectArgs da;
  for (int i = 0; i < NBUF; i++) { da.p[i] = d_in[din_idx[i]]; da.n[i] = in_sizes[din_idx[i]]; }
  detect_kernel<<<NBUF, 256, 0, stream>>>(da, flags);

  // ---- mega preprocessing: transposes + vec converts + LN1, one launch ----
  MegaArgs ma;
  {
    const void* wi[6] = {d_in[6], d_in[8], d_in[10], d_in[12], d_in[14], d_in[16]};
    bf16* wo[6] = {WqkvT, WqkvT + 1024 * 1024, WqkvT + 2 * 1024 * 1024, WoT, W1T, W2T};
    const int wK[6] = {1024, 1024, 1024, 1024, 1024, 4096};
    const int wN[6] = {1024, 1024, 1024, 1024, 4096, 1024};
    const int wf[6] = {5, 7, 9, 11, 13, 15};
    for (int i = 0; i < 6; i++) {
      ma.w_in[i] = wi[i]; ma.w_out[i] = wo[i];
      ma.wK[i] = wK[i]; ma.wN[i] = wN[i]; ma.wflag[i] = wf[i];
    }
    const int vf[10] = {1, 2, 3, 4, 6, 8, 10, 12, 14, 16};
    bf16* vd[10] = {ln1g_c, ln1b_c, ln2g_c, ln2b_c,
                    bqkv_c, bqkv_c + 1024, bqkv_c + 2048, bo_c, b1_c, b2_c};
    for (int i = 0; i < 10; i++) {
      int di = din_idx[vf[i]];
      ma.vp[i] = d_in[di]; ma.vd[i] = vd[i]; ma.vn[i] = in_sizes[di]; ma.vfi[i] = vf[i];
    }
    ma.x = d_in[0]; ma.graw = d_in[2]; ma.braw = d_in[3]; ma.y = xn;
  }
  mega_pre<<<3072 + 1 + TOKENS, dim3(64, 4), 0, stream>>>(ma, flags);

  // ---- pipeline ----
  gemm_qkv<<<dim3(24, 32), 256, 0, stream>>>(xn, WqkvT, bqkv_c, QKbuf, Vtbuf);

  attn_kernel<<<dim3(TSEQ / 256, NHEADS, 2), 512, 0, stream>>>(QKbuf, Vtbuf, ab);

  gemm128<64, 128, EPI_RES, float, bf16><<<dim3(8, 64), 256, 0, stream>>>(
      ab, WoT, bo_c, xn, xmid32, 1024, 1024);

  ln_f32<<<TOKENS, 256, 0, stream>>>(xmid32, ln2g_c, ln2b_c, h2);

  gemm128<128, 128, EPI_GELU, bf16, bf16><<<dim3(32, 32), 256, 0, stream>>>(
      h2, W1T, b1_c, (const bf16*)nullptr, f1, 4096, 1024);

  gemm128<64, 128, EPI_RES, float, float><<<dim3(8, 64), 256, 0, stream>>>(
      f1, W2T, b2_c, xmid32, (float*)d_out, 1024, 4096);
}